// Round 8
// baseline (149.232 us; speedup 1.0000x reference)
//
#include <hip/hip_runtime.h>
#include <hip/hip_fp16.h>

// WeightedMSELoss: mean over [B,2] of |pred-label| * (1 + a - a*w[cell(pred)])
// R7 result: all-nt loads -> kernel ~40.5 us (~3.3 TB/s), up from 51 us
// (2.6 TB/s) with L2-allocating loads. Both short of the ~21 us floor.
// R8 experiment (E1): split the two 67 MB streams across the two delivery
// paths -- pred via NORMAL loads (L2-allocating, ~2.5 TB/s ceiling), labels
// via NT loads (L2-bypass, ~3.3 TB/s ceiling). If the paths are independent
// resources, they overlap -> ~27 us. If they share a wall -> ~40 us (null).

typedef float f32x4 __attribute__((ext_vector_type(4)));

constexpr int   GRIDN  = 201;
constexpr int   GRIDSZ = GRIDN * GRIDN;   // 40401
constexpr float ALPHA  = 0.1f;
constexpr int   NBLK   = 512;

__global__ __launch_bounds__(1024, 8) void wmse_partial(
    const f32x4* __restrict__ pred4,
    const f32x4* __restrict__ lab4,
    const float* __restrict__ wg,
    float*       __restrict__ partials,
    int n4)
{
    __shared__ __half wg_lds[GRIDSZ];         // 80,802 B -> 2 blocks/CU

    // Stage + compress weight grid: vectorized f32x4 -> f16x4 (from L2/L3).
    for (int j = threadIdx.x; j < GRIDSZ / 4; j += 1024) {
        const f32x4 v = ((const f32x4*)wg)[j];
        __half2 h01, h23;
        h01.x = __float2half(v.x); h01.y = __float2half(v.y);
        h23.x = __float2half(v.z); h23.y = __float2half(v.w);
        *reinterpret_cast<__half2*>(&wg_lds[j * 4])     = h01;
        *reinterpret_cast<__half2*>(&wg_lds[j * 4 + 2]) = h23;
    }
    if (threadIdx.x == 0)                     // tail: 40401 = 4*10100 + 1
        wg_lds[GRIDSZ - 1] = __float2half(wg[GRIDSZ - 1]);
    __syncthreads();

    float acc = 0.0f;
    const int stride = gridDim.x * blockDim.x;
    #pragma unroll 4
    for (int i = blockIdx.x * blockDim.x + threadIdx.x; i < n4; i += stride) {
        const f32x4 p = pred4[i];                            // L2 path
        const f32x4 l = __builtin_nontemporal_load(&lab4[i]); // bypass path

        // row 0: (lat, lon) = (p.x, p.y)
        {
            const float e = fabsf(p.x - l.x) + fabsf(p.y - l.y);
            int xi = min(max((int)(p.x * 200.0f), 0), GRIDN - 1);
            int yi = min(max((int)(p.y * 200.0f), 0), GRIDN - 1);
            const float w = __half2float(wg_lds[xi * GRIDN + yi]);
            acc += e * fmaf(-ALPHA, w, 1.0f + ALPHA);
        }
        // row 1: (lat, lon) = (p.z, p.w)
        {
            const float e = fabsf(p.z - l.z) + fabsf(p.w - l.w);
            int xi = min(max((int)(p.z * 200.0f), 0), GRIDN - 1);
            int yi = min(max((int)(p.w * 200.0f), 0), GRIDN - 1);
            const float w = __half2float(wg_lds[xi * GRIDN + yi]);
            acc += e * fmaf(-ALPHA, w, 1.0f + ALPHA);
        }
    }

    // 64-lane wave reduction
    #pragma unroll
    for (int off = 32; off > 0; off >>= 1)
        acc += __shfl_down(acc, off, 64);

    __shared__ float red[16];
    const int lane = threadIdx.x & 63;
    const int wid  = threadIdx.x >> 6;
    if (lane == 0) red[wid] = acc;
    __syncthreads();
    if (threadIdx.x == 0) {
        float s = 0.0f;
        #pragma unroll
        for (int k = 0; k < 16; ++k) s += red[k];
        partials[blockIdx.x] = s;              // plain store; all NBLK written
    }
}

__global__ __launch_bounds__(512) void wmse_final(
    const float* __restrict__ partials, float* __restrict__ out, float scale)
{
    float v = partials[threadIdx.x];           // exactly NBLK=512 threads
    #pragma unroll
    for (int off = 32; off > 0; off >>= 1)
        v += __shfl_down(v, off, 64);
    __shared__ float red[8];
    const int lane = threadIdx.x & 63;
    const int wid  = threadIdx.x >> 6;
    if (lane == 0) red[wid] = v;
    __syncthreads();
    if (threadIdx.x == 0) {
        float s = 0.0f;
        #pragma unroll
        for (int k = 0; k < 8; ++k) s += red[k];
        out[0] = s * scale;
    }
}

extern "C" void kernel_launch(void* const* d_in, const int* in_sizes, int n_in,
                              void* d_out, int out_size, void* d_ws, size_t ws_size,
                              hipStream_t stream) {
    const f32x4* pred = (const f32x4*)d_in[0];
    const f32x4* lab  = (const f32x4*)d_in[1];
    const float* wg   = (const float*)d_in[2];
    float*       out  = (float*)d_out;
    float*       part = (float*)d_ws;         // NBLK floats of scratch

    const long long total = (long long)in_sizes[0];   // B*2 floats
    const int   n4    = (int)(total / 4);             // float4 count per array
    const float scale = 1.0f / (float)total;

    wmse_partial<<<NBLK, 1024, 0, stream>>>(pred, lab, wg, part, n4);
    wmse_final<<<1, 512, 0, stream>>>(part, out, scale);
}

// Round 13
// 141.125 us; speedup vs baseline: 1.0574x; 1.0574x over previous
//
#include <hip/hip_runtime.h>
#include <hip/hip_fp16.h>

// WeightedMSELoss: mean over [B,2] of |pred-label| * (1 + a - a*w[cell(pred)])
// R8: split-path experiment NEGATIVE (normal+nt mix worse than all-nt) ->
// one shared read wall ~3.3 TB/s. All-nt kernel ~40.5 us.
// R9-R12 (last in-kernel lever): overlap the serial LDS-staging phase with
// the stream -- issue the first 4 load-pairs BEFORE staging, then a depth-4
// register rotation (consume k / issue k+4). Keeps VGPR <= 64 (32 waves/CU).

typedef float f32x4 __attribute__((ext_vector_type(4)));

constexpr int   GRIDN  = 201;
constexpr int   GRIDSZ = GRIDN * GRIDN;   // 40401
constexpr float ALPHA  = 0.1f;
constexpr int   NBLK   = 512;
constexpr int   TPB    = 1024;

__device__ __forceinline__ float cell_term(float px, float py, float lx, float ly,
                                           const __half* __restrict__ wg_lds)
{
    const float e = fabsf(px - lx) + fabsf(py - ly);
    // floor((p*180-90)/0.9)+100 == floor(p*200); p in [0,1) so trunc==floor
    const int xi = min(max((int)(px * 200.0f), 0), GRIDN - 1);
    const int yi = min(max((int)(py * 200.0f), 0), GRIDN - 1);
    const float w = __half2float(wg_lds[xi * GRIDN + yi]);
    return e * fmaf(-ALPHA, w, 1.0f + ALPHA);
}

__global__ __launch_bounds__(1024, 8) void wmse_partial(
    const f32x4* __restrict__ pred4,
    const f32x4* __restrict__ lab4,
    const float* __restrict__ wg,
    float*       __restrict__ partials,
    int n4)
{
    __shared__ __half wg_lds[GRIDSZ];         // 80,802 B -> 2 blocks/CU

    const int tid0   = blockIdx.x * TPB + threadIdx.x;
    const int stride = gridDim.x * TPB;
    float acc = 0.0f;

    if (n4 == 8 * stride) {
        // ---- fast path: exactly 8 iterations/thread ----
        // Issue first 4 load-pairs now; they fly while we stage the table.
        f32x4 p0 = __builtin_nontemporal_load(&pred4[tid0]);
        f32x4 l0 = __builtin_nontemporal_load(&lab4[tid0]);
        f32x4 p1 = __builtin_nontemporal_load(&pred4[tid0 + stride]);
        f32x4 l1 = __builtin_nontemporal_load(&lab4[tid0 + stride]);
        f32x4 p2 = __builtin_nontemporal_load(&pred4[tid0 + 2 * stride]);
        f32x4 l2 = __builtin_nontemporal_load(&lab4[tid0 + 2 * stride]);
        f32x4 p3 = __builtin_nontemporal_load(&pred4[tid0 + 3 * stride]);
        f32x4 l3 = __builtin_nontemporal_load(&lab4[tid0 + 3 * stride]);

        // Stage + compress weight grid (normal loads: L2-hit for later blocks).
        for (int j = threadIdx.x; j < GRIDSZ / 4; j += TPB) {
            const f32x4 v = ((const f32x4*)wg)[j];
            __half2 h01, h23;
            h01.x = __float2half(v.x); h01.y = __float2half(v.y);
            h23.x = __float2half(v.z); h23.y = __float2half(v.w);
            *reinterpret_cast<__half2*>(&wg_lds[j * 4])     = h01;
            *reinterpret_cast<__half2*>(&wg_lds[j * 4 + 2]) = h23;
        }
        if (threadIdx.x == 0)                 // tail: 40401 = 4*10100 + 1
            wg_lds[GRIDSZ - 1] = __float2half(wg[GRIDSZ - 1]);
        __syncthreads();

        // Depth-4 rotation: consume k, issue k+4.
        acc += cell_term(p0.x, p0.y, l0.x, l0.y, wg_lds);
        acc += cell_term(p0.z, p0.w, l0.z, l0.w, wg_lds);
        p0 = __builtin_nontemporal_load(&pred4[tid0 + 4 * stride]);
        l0 = __builtin_nontemporal_load(&lab4[tid0 + 4 * stride]);

        acc += cell_term(p1.x, p1.y, l1.x, l1.y, wg_lds);
        acc += cell_term(p1.z, p1.w, l1.z, l1.w, wg_lds);
        p1 = __builtin_nontemporal_load(&pred4[tid0 + 5 * stride]);
        l1 = __builtin_nontemporal_load(&lab4[tid0 + 5 * stride]);

        acc += cell_term(p2.x, p2.y, l2.x, l2.y, wg_lds);
        acc += cell_term(p2.z, p2.w, l2.z, l2.w, wg_lds);
        p2 = __builtin_nontemporal_load(&pred4[tid0 + 6 * stride]);
        l2 = __builtin_nontemporal_load(&lab4[tid0 + 6 * stride]);

        acc += cell_term(p3.x, p3.y, l3.x, l3.y, wg_lds);
        acc += cell_term(p3.z, p3.w, l3.z, l3.w, wg_lds);
        p3 = __builtin_nontemporal_load(&pred4[tid0 + 7 * stride]);
        l3 = __builtin_nontemporal_load(&lab4[tid0 + 7 * stride]);

        acc += cell_term(p0.x, p0.y, l0.x, l0.y, wg_lds);
        acc += cell_term(p0.z, p0.w, l0.z, l0.w, wg_lds);
        acc += cell_term(p1.x, p1.y, l1.x, l1.y, wg_lds);
        acc += cell_term(p1.z, p1.w, l1.z, l1.w, wg_lds);
        acc += cell_term(p2.x, p2.y, l2.x, l2.y, wg_lds);
        acc += cell_term(p2.z, p2.w, l2.z, l2.w, wg_lds);
        acc += cell_term(p3.x, p3.y, l3.x, l3.y, wg_lds);
        acc += cell_term(p3.z, p3.w, l3.z, l3.w, wg_lds);
    } else {
        // ---- generic fallback (R7 structure) ----
        for (int j = threadIdx.x; j < GRIDSZ / 4; j += TPB) {
            const f32x4 v = ((const f32x4*)wg)[j];
            __half2 h01, h23;
            h01.x = __float2half(v.x); h01.y = __float2half(v.y);
            h23.x = __float2half(v.z); h23.y = __float2half(v.w);
            *reinterpret_cast<__half2*>(&wg_lds[j * 4])     = h01;
            *reinterpret_cast<__half2*>(&wg_lds[j * 4 + 2]) = h23;
        }
        if (threadIdx.x == 0)
            wg_lds[GRIDSZ - 1] = __float2half(wg[GRIDSZ - 1]);
        __syncthreads();

        #pragma unroll 4
        for (int i = tid0; i < n4; i += stride) {
            const f32x4 p = __builtin_nontemporal_load(&pred4[i]);
            const f32x4 l = __builtin_nontemporal_load(&lab4[i]);
            acc += cell_term(p.x, p.y, l.x, l.y, wg_lds);
            acc += cell_term(p.z, p.w, l.z, l.w, wg_lds);
        }
    }

    // 64-lane wave reduction
    #pragma unroll
    for (int off = 32; off > 0; off >>= 1)
        acc += __shfl_down(acc, off, 64);

    __shared__ float red[16];
    const int lane = threadIdx.x & 63;
    const int wid  = threadIdx.x >> 6;
    if (lane == 0) red[wid] = acc;
    __syncthreads();
    if (threadIdx.x == 0) {
        float s = 0.0f;
        #pragma unroll
        for (int k = 0; k < 16; ++k) s += red[k];
        partials[blockIdx.x] = s;              // plain store; all NBLK written
    }
}

__global__ __launch_bounds__(512) void wmse_final(
    const float* __restrict__ partials, float* __restrict__ out, float scale)
{
    float v = partials[threadIdx.x];           // exactly NBLK=512 threads
    #pragma unroll
    for (int off = 32; off > 0; off >>= 1)
        v += __shfl_down(v, off, 64);
    __shared__ float red[8];
    const int lane = threadIdx.x & 63;
    const int wid  = threadIdx.x >> 6;
    if (lane == 0) red[wid] = v;
    __syncthreads();
    if (threadIdx.x == 0) {
        float s = 0.0f;
        #pragma unroll
        for (int k = 0; k < 8; ++k) s += red[k];
        out[0] = s * scale;
    }
}

extern "C" void kernel_launch(void* const* d_in, const int* in_sizes, int n_in,
                              void* d_out, int out_size, void* d_ws, size_t ws_size,
                              hipStream_t stream) {
    const f32x4* pred = (const f32x4*)d_in[0];
    const f32x4* lab  = (const f32x4*)d_in[1];
    const float* wg   = (const float*)d_in[2];
    float*       out  = (float*)d_out;
    float*       part = (float*)d_ws;         // NBLK floats of scratch

    const long long total = (long long)in_sizes[0];   // B*2 floats
    const int   n4    = (int)(total / 4);             // float4 count per array
    const float scale = 1.0f / (float)total;

    wmse_partial<<<NBLK, TPB, 0, stream>>>(pred, lab, wg, part, n4);
    wmse_final<<<1, 512, 0, stream>>>(part, out, scale);
}